// Round 12
// baseline (143.909 us; speedup 1.0000x reference)
//
#include <hip/hip_runtime.h>
#include <hip/hip_bf16.h>

// LSTM_71382356459716 R11: R10 (barrier-free, wave-independent LSTM) with the
// LDS row-stride bug fixed: h occupies positions p=0..63 per row, but R10 had
// HP=40 -> cross-row h corruption (absmax 0.26, bounded -- exactly collided-h
// signature). HP=72 (144 B = 9*16 B, odd multiple -> bank rotation, 16B-aligned
// b128 ops). Everything else identical to R10:
//   each WAVE owns 16 batch rows x ALL 256 gates; A = 16 M-tiles stationary
//   (~192 VGPR, 1 wave/SIMD via waves_per_eu(1,1)); 48 MFMA/step; h exchange
//   wave-private through per-wave LDS (2 ds_write_b128 + 2 ds_read_b128,
//   same-wave in-order, NO __syncthreads in the loop); x per-wave-exclusive
//   direct-from-global, packed in-register; unit permutation
//   sigma(u=4mt+q)=16q+mt baked into prep W_hh and FC index.
// Numerics = R9: exp2-prescaled weights (log2e / 2log2e), c in scaled units,
// rcp-grouped {i,f,g} + {o,c}: 7 trans/tuple. 256 blocks = 1 wave/SIMD.

namespace {
constexpr int B_TOT   = 16384;
constexpr int T_STEPS = 28;
constexpr int IN_DIM  = 28;
constexpr int HID     = 64;
constexpr int OUT_DIM = 10;
constexpr int RPW     = 16;     // rows per wave
constexpr int THREADS = 256;    // 4 independent waves
constexpr int HP      = 72;     // h row stride in shorts (144 B = 9*16B, odd)
constexpr int XROW    = T_STEPS * IN_DIM;  // 784 floats per batch row
constexpr int WS_ELEMS = 48 * 64 * 8;      // 16 mt * 3 kc frags = 48 KB
}

typedef __attribute__((ext_vector_type(8))) short short8v;   // 8 bf16
typedef __attribute__((ext_vector_type(4))) short short4v;
typedef __attribute__((ext_vector_type(4))) float float4v;
typedef __attribute__((ext_vector_type(4))) int   int4v;

__device__ __forceinline__ short f2bf_cold(float f) {
  union { float f; unsigned u; } v; v.f = f;
  unsigned r = v.u + 0x7FFFu + ((v.u >> 16) & 1u);
  return (short)(r >> 16);
}
__device__ __forceinline__ float bf2f(short s) {
  union { unsigned u; float f; } v; v.u = ((unsigned)(unsigned short)s) << 16;
  return v.f;
}
__device__ __forceinline__ unsigned pk2(float a, float b) {  // 2xf32->bf16x2
  __hip_bfloat162 h = __float22bfloat162_rn(float2{a, b});
  union { __hip_bfloat162 h; unsigned u; } cv; cv.h = h; return cv.u;
}

// ---- setup: permute+prescale weights into MFMA A-frag order ----------------
// Frag f = mt*3 + kc (mt 0..15), lane l, elem j:
//   ws[(f*64+l)*8+j] = bf16( scale(type) * Araw[m=16*mt+(l&15)][k] ),
//   k = kc*32 + (l>>4)*8 + j.
// gate row g = (m&3)*64 + (m>>2); scale = log2e (i,f,o) / 2*log2e (g).
// k<28 -> W_ih; k==28 -> b_ih+b_hh (x col 28 == 1); 29..31 -> 0;
// k>=32 -> W_hh column through sigma^-1: p = k-32, u = 4*(p&15) + (p>>4).
__global__ void lstm_prep(const float* __restrict__ W_ih,
                          const float* __restrict__ W_hh,
                          const float* __restrict__ b_ih,
                          const float* __restrict__ b_hh,
                          unsigned short* __restrict__ ws) {
  int idx = blockIdx.x * blockDim.x + threadIdx.x;
  if (idx >= WS_ELEMS) return;
  int j  = idx & 7;
  int l  = (idx >> 3) & 63;
  int fk = idx >> 9;            // mt*3 + kc
  int kc = fk % 3;
  int mt = fk / 3;
  int m  = 16 * mt + (l & 15);
  int unit = m >> 2, type = m & 3;
  int g  = type * 64 + unit;
  int k  = kc * 32 + (l >> 4) * 8 + j;
  float v = 0.0f;
  if (k < IN_DIM)        v = W_ih[g * IN_DIM + k];
  else if (k == IN_DIM)  v = b_ih[g] + b_hh[g];
  else if (k >= 32) {
    int p = k - 32;
    int u = 4 * (p & 15) + (p >> 4);
    v = W_hh[g * HID + u];
  }
  v *= (type == 2) ? 2.8853900817779268f : 1.4426950408889634f;
  ws[idx] = (unsigned short)f2bf_cold(v);
}

__global__ __attribute__((amdgpu_flat_work_group_size(THREADS, THREADS),
                          amdgpu_waves_per_eu(1, 1)))
void lstm_mfma11(const float* __restrict__ x,
                 const unsigned short* __restrict__ wfrag,
                 const float* __restrict__ W_fc,
                 const float* __restrict__ b_fc, float* __restrict__ out) {
  __shared__ short hs[4][RPW][HP];   // per-wave h region, position p=16q+mt (p<64)

  const int tid  = threadIdx.x;
  const int lane = tid & 63;
  const int w    = tid >> 6;      // wave 0..3, fully independent after init
  const int l15  = lane & 15;
  const int q    = lane >> 4;     // 0..3
  const int row  = blockIdx.x * (4 * RPW) + 16 * w + l15;  // this lane's batch row

  // ---- stationary A: all 16 M-tiles, 48 coalesced b128 loads per lane ------
  short8v a[16][3];
#pragma unroll
  for (int i = 0; i < 16; ++i)
#pragma unroll
    for (int kc = 0; kc < 3; ++kc)
      a[i][kc] = *(const short8v*)&wfrag[(((i * 3) + kc) * 64 + lane) * 8];

  // zero all h regions once (init-only barrier; none inside the loop)
  for (int idx = tid; idx < 4 * RPW * HP; idx += THREADS) (&hs[0][0][0])[idx] = 0;
  __syncthreads();

  short (*hsw)[HP] = hs[w];       // this wave's private region

  // ---- x direct-from-global: lane (q,l15) covers its row, k = q*8..q*8+7 ---
  const float* xrow = x + (size_t)row * XROW + q * 8;
  float4 lo = *(const float4*)xrow;                       // t = 0
  float4 hi = {0.f, 0.f, 0.f, 0.f};
  if (q < 3) hi = *(const float4*)(xrow + 4);
  else       hi.x = 1.0f;          // k==28 constant-1 feeds the bias column

  float c_state[16];
#pragma unroll
  for (int i = 0; i < 16; ++i) c_state[i] = 0.0f;

  for (int t = 0; t < T_STEPS; ++t) {
    // pack this step's x B-frag (consumes lo/hi loaded last iteration)
    int4v xi;
    xi[0] = pk2(lo.x, lo.y); xi[1] = pk2(lo.z, lo.w);
    xi[2] = pk2(hi.x, hi.y); xi[3] = pk2(hi.z, hi.w);
    union { int4v i; short8v s; } xb; xb.i = xi;

    // h B-frags from this wave's LDS region (written by this wave last step;
    // same-wave DS ordering, no barrier): p = 8q+j (kchunk1), 32+8q+j (kchunk2)
    short8v hf1 = *(const short8v*)&hsw[l15][8 * q];
    short8v hf2 = *(const short8v*)&hsw[l15][32 + 8 * q];

    // prefetch next step's x (a full step of slack before consumption)
    if (t + 1 < T_STEPS) {
      const float* xp = xrow + (t + 1) * IN_DIM;
      lo = *(const float4*)xp;
      if (q < 3) hi = *(const float4*)(xp + 4);
    }

    const float4v zero4 = {0.f, 0.f, 0.f, 0.f};
    float4v acc[16];
#pragma unroll
    for (int i = 0; i < 16; ++i)
      acc[i] = __builtin_amdgcn_mfma_f32_16x16x32_bf16(a[i][0], xb.s, zero4, 0, 0, 0);
#pragma unroll
    for (int i = 0; i < 16; ++i)
      acc[i] = __builtin_amdgcn_mfma_f32_16x16x32_bf16(a[i][1], hf1, acc[i], 0, 0, 0);
#pragma unroll
    for (int i = 0; i < 16; ++i)
      acc[i] = __builtin_amdgcn_mfma_f32_16x16x32_bf16(a[i][2], hf2, acc[i], 0, 0, 0);

    // activations (R9 numerics): 16 independent tuples -> deep trans ILP.
    // Lane's tuple i = unit 4i+q, row l15 (C/D: col=l15, row=4q+reg).
    float hv[16];
#pragma unroll
    for (int i = 0; i < 16; ++i) {
      float4v g4 = acc[i];
      float Ei = __builtin_amdgcn_exp2f(-g4[0]);
      float Ef = __builtin_amdgcn_exp2f(-g4[1]);
      float Eg = __builtin_amdgcn_exp2f(-g4[2]);
      float di = 1.0f + Ei, df = 1.0f + Ef, dg = 1.0f + Eg;
      float t1 = di * df;
      float r1 = __builtin_amdgcn_rcpf(t1 * dg);
      float iv = r1 * (df * dg);
      float fv = r1 * (di * dg);
      float gnum = fmaf(-Eg, 2.8853900817779268f, 2.8853900817779268f);
      float gv = (r1 * t1) * gnum;
      float cn = fmaf(fv, c_state[i], iv * gv);
      c_state[i] = cn;
      float ct = fminf(fmaxf(cn, -44.0f), 44.0f);
      float Eo = __builtin_amdgcn_exp2f(-g4[3]);
      float Ec = __builtin_amdgcn_exp2f(-ct);
      float dn = 1.0f + Eo, dc = 1.0f + Ec;
      float r2 = __builtin_amdgcn_rcpf(dn * dc);
      float ov = r2 * dc;                 // sigma(o)
      float tc = (r2 * dn) * (1.0f - Ec); // tanh(c)
      hv[i] = ov * tc;
    }

    // store 16 h values as TWO b128 at positions p = 16q + mt (pairs packed)
    union { unsigned u[8]; short8v s[2]; } pw;
#pragma unroll
    for (int e = 0; e < 8; ++e) pw.u[e] = pk2(hv[2 * e], hv[2 * e + 1]);
    *(short8v*)&hsw[l15][16 * q]     = pw.s[0];
    *(short8v*)&hsw[l15][16 * q + 8] = pw.s[1];
    // no barrier: next iteration's ds_read is same-wave, in-order
  }

  // ---- FC epilogue, wave-local: rows 16w..16w+15, final h in hsw -----------
  // lane (q,l15): outputs o = q, q+4, q+8 (o<10) for row l15.
#pragma unroll
  for (int c = 0; c < 3; ++c) {
    const int o = q + 4 * c;
    if (o < OUT_DIM) {
      float sacc = b_fc[o];
#pragma unroll
      for (int p = 0; p < HID; ++p) {
        const int u = 4 * (p & 15) + (p >> 4);   // sigma^-1(p)
        sacc += bf2f(hsw[l15][p]) * W_fc[o * HID + u];
      }
      out[(size_t)row * OUT_DIM + o] = sacc;
    }
  }
}

extern "C" void kernel_launch(void* const* d_in, const int* in_sizes, int n_in,
                              void* d_out, int out_size, void* d_ws, size_t ws_size,
                              hipStream_t stream) {
  const float* x    = (const float*)d_in[0];
  const float* W_ih = (const float*)d_in[1];
  const float* W_hh = (const float*)d_in[2];
  const float* b_ih = (const float*)d_in[3];
  const float* b_hh = (const float*)d_in[4];
  const float* W_fc = (const float*)d_in[5];
  const float* b_fc = (const float*)d_in[6];
  float* out = (float*)d_out;
  unsigned short* ws = (unsigned short*)d_ws;   // 48 KB frag-ordered weights

  lstm_prep<<<(WS_ELEMS + 255) / 256, 256, 0, stream>>>(W_ih, W_hh, b_ih, b_hh, ws);

  dim3 grid(B_TOT / (4 * RPW));  // 256 blocks -> 1 block/CU, 1 wave/SIMD
  dim3 block(THREADS);
  lstm_mfma11<<<grid, block, 0, stream>>>(x, ws, W_fc, b_fc, out);
}

// Round 13
// 132.582 us; speedup vs baseline: 1.0854x; 1.0854x over previous
//
#include <hip/hip_runtime.h>
#include <hip/hip_bf16.h>

// LSTM_71382356459716 R12: cohort-pipelined R9.
// R11 verdict: barrier-free @ 1 wave/SIMD = 72.6us (worse than R9's 57.8) --
// lost TLP exposes the recurrence chain; barrier wasn't the poison. Model:
// issue ~3300 cyc/SIMD/step (trans 1792 + fullrate ~800 + MFMA ~750), R9
// wall 4950 -> ~1700 stall. Fix: each block owns TWO 16-row cohorts (32
// rows, grid 512, 2 blocks/CU): per step each wave runs MFMA(A), MFMA(B),
// ACT(A), ACT(B) -- B's MFMAs are independent of A's activation chain
// (intra-wave trans/MFMA overlap), and the single per-step barrier is
// amortized over 2x work. A-frags shared across cohorts.
// Numerics/layout = R9: exp2-prescaled frag-ordered weights from prep
// (log2e / 2log2e, sigma(u=4mt+q)=16q+... same 16*(p>>4)+4*(p&3)+((p>>2)&3)
// FC permutation), c in 2log2e-scaled units, rcp groups {i,f,g}+{o,c},
// bias col 28 vs constant-1 x col, 3 ds_read_b128 B-frags + 1 ds_write_b64
// h-store per cohort, double-buffered 104-short rows.

namespace {
constexpr int B_TOT   = 16384;
constexpr int T_STEPS = 28;
constexpr int IN_DIM  = 28;
constexpr int HID     = 64;
constexpr int OUT_DIM = 10;
constexpr int RPC     = 16;    // rows per cohort
constexpr int NCOH    = 2;     // cohorts per block -> 32 rows/block
constexpr int THREADS = 256;   // 4 waves
constexpr int KP      = 104;   // row stride in shorts (208 B, odd*16B)
constexpr int XROW    = T_STEPS * IN_DIM;  // 784 floats per batch row
constexpr int WS_ELEMS = 48 * 64 * 8;      // 48 KB frag-ordered weights
}

typedef __attribute__((ext_vector_type(8))) short short8v;   // 8 bf16
typedef __attribute__((ext_vector_type(4))) short short4v;
typedef __attribute__((ext_vector_type(4))) float float4v;

__device__ __forceinline__ short f2bf_cold(float f) {
  union { float f; unsigned u; } v; v.f = f;
  unsigned r = v.u + 0x7FFFu + ((v.u >> 16) & 1u);
  return (short)(r >> 16);
}
__device__ __forceinline__ float bf2f(short s) {
  union { unsigned u; float f; } v; v.u = ((unsigned)(unsigned short)s) << 16;
  return v.f;
}
__device__ __forceinline__ unsigned pk2(float a, float b) {  // 2xf32->bf16x2
  __hip_bfloat162 h = __float22bfloat162_rn(float2{a, b});
  union { __hip_bfloat162 h; unsigned u; } cv; cv.h = h; return cv.u;
}

// ---- setup: permute+prescale weights into MFMA A-frag order (== R9) --------
__global__ void lstm_prep(const float* __restrict__ W_ih,
                          const float* __restrict__ W_hh,
                          const float* __restrict__ b_ih,
                          const float* __restrict__ b_hh,
                          unsigned short* __restrict__ ws) {
  int idx = blockIdx.x * blockDim.x + threadIdx.x;
  if (idx >= WS_ELEMS) return;
  int j  = idx & 7;
  int l  = (idx >> 3) & 63;
  int fk = idx >> 9;            // mt*3 + kc  (mt = 4*w + i, 16 total)
  int kc = fk % 3;
  int mt = fk / 3;
  int m  = 16 * mt + (l & 15);
  int unit = m >> 2, type = m & 3;
  int g  = type * 64 + unit;
  int k  = kc * 32 + (l >> 4) * 8 + j;
  float v = 0.0f;
  if (k < IN_DIM)        v = W_ih[g * IN_DIM + k];
  else if (k == IN_DIM)  v = b_ih[g] + b_hh[g];
  else if (k >= 32) {
    int p = k - 32;
    int u = 16 * (p >> 4) + 4 * (p & 3) + ((p >> 2) & 3);  // sigma^-1
    v = W_hh[g * HID + u];
  }
  v *= (type == 2) ? 2.8853900817779268f : 1.4426950408889634f;
  ws[idx] = (unsigned short)f2bf_cold(v);
}

__device__ __forceinline__ void act_tuple(const float4v g4, float& c,
                                          float& hv) {
  float Ei = __builtin_amdgcn_exp2f(-g4[0]);
  float Ef = __builtin_amdgcn_exp2f(-g4[1]);
  float Eg = __builtin_amdgcn_exp2f(-g4[2]);
  float di = 1.0f + Ei, df = 1.0f + Ef, dg = 1.0f + Eg;
  float t1 = di * df;
  float r1 = __builtin_amdgcn_rcpf(t1 * dg);
  float iv = r1 * (df * dg);
  float fv = r1 * (di * dg);
  float gnum = fmaf(-Eg, 2.8853900817779268f, 2.8853900817779268f);
  float gv = (r1 * t1) * gnum;
  float cn = fmaf(fv, c, iv * gv);
  c = cn;
  float ct = fminf(fmaxf(cn, -44.0f), 44.0f);
  float Eo = __builtin_amdgcn_exp2f(-g4[3]);
  float Ec = __builtin_amdgcn_exp2f(-ct);
  float dn = 1.0f + Eo, dc = 1.0f + Ec;
  float r2 = __builtin_amdgcn_rcpf(dn * dc);
  float ov = r2 * dc;                 // sigma(o)
  float tc = (r2 * dn) * (1.0f - Ec); // tanh(c)
  hv = ov * tc;
}

__global__ __attribute__((amdgpu_flat_work_group_size(THREADS, THREADS),
                          amdgpu_waves_per_eu(2, 2)))
void lstm_mfma12(const float* __restrict__ x,
                 const unsigned short* __restrict__ wfrag,
                 const float* __restrict__ W_fc,
                 const float* __restrict__ b_fc, float* __restrict__ out) {
  // [cohort][buf][row][k]: k 0..27 x, 28 = 1.0, 32..95 h (permuted). 26 KB.
  __shared__ short hs[NCOH][2][RPC][KP];

  const int tid  = threadIdx.x;
  const int lane = tid & 63;
  const int w    = tid >> 6;      // wave 0..3 -> units 16w..16w+15
  const int l15  = lane & 15;
  const int q    = lane >> 4;     // 0..3
  const int b0   = blockIdx.x * (NCOH * RPC);   // 32 rows per block

  // ---- stationary A: 12 coalesced 16B loads per lane (shared by cohorts) ---
  short8v a[4][3];
#pragma unroll
  for (int i = 0; i < 4; ++i)
#pragma unroll
    for (int kc = 0; kc < 3; ++kc)
      a[i][kc] = *(const short8v*)&wfrag[((((4 * w + i) * 3) + kc) * 64 + lane) * 8];

  // zero both cohorts' buffers, set constant bias columns
  for (int idx = tid; idx < NCOH * 2 * RPC * KP; idx += THREADS)
    (&hs[0][0][0][0])[idx] = 0;
  __syncthreads();
  if (tid < NCOH * 2 * RPC) {
    int coh = tid >> 5, buf = (tid >> 4) & 1, r = tid & 15;
    hs[coh][buf][r][IN_DIM] = (short)0x3F80;  // bf16 1.0
  }

  // ---- x staging: 224 stager lanes (56 per wave), one float4 each ----------
  const int  s  = w * 56 + lane;        // 0..223 for lane<56
  const bool stager = (lane < 56);
  const int  sr = s / 7;                // block-row 0..31
  const int  sc = s - 7 * sr;           // col-group 0..6
  const int  scoh = sr >> 4, srow = sr & 15;
  const float* xptr = x + (size_t)(b0 + sr) * XROW + sc * 4;

  float4 xfly = {0.f, 0.f, 0.f, 0.f};
  if (stager) {
    float4 x0 = *(const float4*)xptr;
    short4v sv;
    unsigned plo = pk2(x0.x, x0.y), phi = pk2(x0.z, x0.w);
    sv[0] = (short)(plo & 0xFFFF); sv[1] = (short)(plo >> 16);
    sv[2] = (short)(phi & 0xFFFF); sv[3] = (short)(phi >> 16);
    *(short4v*)&hs[scoh][0][srow][sc * 4] = sv;
    xfly = *(const float4*)(xptr + 1 * IN_DIM);   // x_1, consumed at t=0
  }
  __syncthreads();

  float c_state[NCOH][4] = {{0.f, 0.f, 0.f, 0.f}, {0.f, 0.f, 0.f, 0.f}};

  for (int t = 0; t < T_STEPS; ++t) {
    const int cur = t & 1, nxt = cur ^ 1;

    // B-frags for BOTH cohorts up front (independent ds_reads)
    short8v bfA0 = *(const short8v*)&hs[0][cur][l15][q * 8];
    short8v bfA1 = *(const short8v*)&hs[0][cur][l15][32 + q * 8];
    short8v bfA2 = *(const short8v*)&hs[0][cur][l15][64 + q * 8];
    short8v bfB0 = *(const short8v*)&hs[1][cur][l15][q * 8];
    short8v bfB1 = *(const short8v*)&hs[1][cur][l15][32 + q * 8];
    short8v bfB2 = *(const short8v*)&hs[1][cur][l15][64 + q * 8];

    // stager: store x_{t+1} (loaded a full step ago), issue load of x_{t+2}
    if (stager) {
      if (t + 1 < T_STEPS) {
        short4v sv;
        unsigned plo = pk2(xfly.x, xfly.y), phi = pk2(xfly.z, xfly.w);
        sv[0] = (short)(plo & 0xFFFF); sv[1] = (short)(plo >> 16);
        sv[2] = (short)(phi & 0xFFFF); sv[3] = (short)(phi >> 16);
        *(short4v*)&hs[scoh][nxt][srow][sc * 4] = sv;
      }
      if (t + 2 < T_STEPS)
        xfly = *(const float4*)(xptr + (t + 2) * IN_DIM);
    }

    const float4v zero4 = {0.f, 0.f, 0.f, 0.f};
    float4v accA[4], accB[4];
#pragma unroll
    for (int i = 0; i < 4; ++i)
      accA[i] = __builtin_amdgcn_mfma_f32_16x16x32_bf16(a[i][0], bfA0, zero4, 0, 0, 0);
#pragma unroll
    for (int i = 0; i < 4; ++i)
      accA[i] = __builtin_amdgcn_mfma_f32_16x16x32_bf16(a[i][1], bfA1, accA[i], 0, 0, 0);
#pragma unroll
    for (int i = 0; i < 4; ++i)
      accA[i] = __builtin_amdgcn_mfma_f32_16x16x32_bf16(a[i][2], bfA2, accA[i], 0, 0, 0);
    // cohort B MFMAs are independent of cohort A's activation chain; the
    // scheduler can overlap them with A's trans ops below.
#pragma unroll
    for (int i = 0; i < 4; ++i)
      accB[i] = __builtin_amdgcn_mfma_f32_16x16x32_bf16(a[i][0], bfB0, zero4, 0, 0, 0);
#pragma unroll
    for (int i = 0; i < 4; ++i)
      accB[i] = __builtin_amdgcn_mfma_f32_16x16x32_bf16(a[i][1], bfB1, accB[i], 0, 0, 0);
#pragma unroll
    for (int i = 0; i < 4; ++i)
      accB[i] = __builtin_amdgcn_mfma_f32_16x16x32_bf16(a[i][2], bfB2, accB[i], 0, 0, 0);

    // activations + h stores, cohort A then B (independent chains)
    {
      float hv[4];
#pragma unroll
      for (int i = 0; i < 4; ++i) act_tuple(accA[i], c_state[0][i], hv[i]);
      unsigned p01 = pk2(hv[0], hv[1]);
      unsigned p23 = pk2(hv[2], hv[3]);
      union { unsigned u[2]; short4v s4; } pw;
      pw.u[0] = p01; pw.u[1] = p23;
      *(short4v*)&hs[0][nxt][l15][32 + 16 * w + 4 * q] = pw.s4;
    }
    {
      float hv[4];
#pragma unroll
      for (int i = 0; i < 4; ++i) act_tuple(accB[i], c_state[1][i], hv[i]);
      unsigned p01 = pk2(hv[0], hv[1]);
      unsigned p23 = pk2(hv[2], hv[3]);
      union { unsigned u[2]; short4v s4; } pw;
      pw.u[0] = p01; pw.u[1] = p23;
      *(short4v*)&hs[1][nxt][l15][32 + 16 * w + 4 * q] = pw.s4;
    }

    __syncthreads();   // one barrier per step, covers both cohorts
  }

  // ---- FC epilogue: final h in buf 0; 320 outputs over 256 threads ---------
  for (int base = 0; base < NCOH * RPC * OUT_DIM; base += THREADS) {
    int idx = base + tid;
    if (idx < NCOH * RPC * OUT_DIM) {
      const int r = idx / OUT_DIM;        // block-row 0..31
      const int o = idx - r * OUT_DIM;
      const int coh = r >> 4, rr = r & 15;
      float sacc = b_fc[o];
#pragma unroll
      for (int p = 0; p < HID; ++p) {
        const int u = 16 * (p >> 4) + 4 * (p & 3) + ((p >> 2) & 3);
        sacc += bf2f(hs[coh][0][rr][32 + p]) * W_fc[o * HID + u];
      }
      out[(size_t)(b0 + r) * OUT_DIM + o] = sacc;
    }
  }
}

extern "C" void kernel_launch(void* const* d_in, const int* in_sizes, int n_in,
                              void* d_out, int out_size, void* d_ws, size_t ws_size,
                              hipStream_t stream) {
  const float* x    = (const float*)d_in[0];
  const float* W_ih = (const float*)d_in[1];
  const float* W_hh = (const float*)d_in[2];
  const float* b_ih = (const float*)d_in[3];
  const float* b_hh = (const float*)d_in[4];
  const float* W_fc = (const float*)d_in[5];
  const float* b_fc = (const float*)d_in[6];
  float* out = (float*)d_out;
  unsigned short* ws = (unsigned short*)d_ws;   // 48 KB frag-ordered weights

  lstm_prep<<<(WS_ELEMS + 255) / 256, 256, 0, stream>>>(W_ih, W_hh, b_ih, b_hh, ws);

  dim3 grid(B_TOT / (NCOH * RPC));  // 512 blocks -> 2 blocks/CU, 2 waves/SIMD
  dim3 block(THREADS);
  lstm_mfma12<<<grid, block, 0, stream>>>(x, ws, W_fc, b_fc, out);
}